// Round 2
// baseline (883.066 us; speedup 1.0000x reference)
//
#include <hip/hip_runtime.h>

// Equivariant linear: segments (u,i) = (64,1),(32,3),(16,5); in==out, 240 cols.
// o[n,v,i] = (1/sqrt(u)) * sum_u x[n,u,i] * w[u,v], per segment.
//
// R2: LDS-bandwidth fix. R1 showed occupancy 2x with zero speedup -> per-CU
// shared-resource bound. The x-broadcast-through-LDS structure moved ~280 KB
// per wave through the LDS pipe (~133 us/CU at measured b128 throughput).
// Now: x is read DIRECTLY from global (L1/L2/L3-resident; broadcast lanes
// coalesce), outputs accumulate in registers and store straight to global.
// Each lane computes multiple v per row (register tiling) to divide the
// x re-read factor. Only w (21.5 KB) lives in LDS. No x LDS, no tile staging.
// Wave = 16 rows, block = 4 waves = 64 rows, grid = 200000/64 = 3125 exact.

#define BLOCK 256
#define RPB 64            // rows per block
#define RPW 16            // rows per wave

#define FMA4(acc, q, w0, w1, w2, w3)                         \
    acc.x += q.x*w0.x + q.y*w1.x + q.z*w2.x + q.w*w3.x;      \
    acc.y += q.x*w0.y + q.y*w1.y + q.z*w2.y + q.w*w3.y;      \
    acc.z += q.x*w0.z + q.y*w1.z + q.z*w2.z + q.w*w3.z;      \
    acc.w += q.x*w0.w + q.y*w1.w + q.z*w2.w + q.w*w3.w;

__global__ __launch_bounds__(BLOCK, 5) void eqlin_kernel(
    const float* __restrict__ x, const float* __restrict__ w,
    float* __restrict__ out, int nrows)
{
    __shared__ __align__(16) float ws[5376];   // 21504 B: weights only

    const int tid = threadIdx.x;
    // ---- stage weights (1344 float4) ----
    {
        const float4* wg = (const float4*)w;
        float4* wl = (float4*)ws;
        #pragma unroll 2
        for (int idx = tid; idx < 1344; idx += BLOCK) wl[idx] = wg[idx];
    }
    __syncthreads();

    const int lane = tid & 63;
    const int wvid = tid >> 6;
    const int rowbase = blockIdx.x * RPB + wvid * RPW;
    if (rowbase >= nrows) return;

    // ============ segment 0: u=v=64, i=1, cols [0,64) ============
    // lane = 16 v-groups (4 v each) x 4 row-groups (4 rows each)
    {
        const int vg = lane & 15;          // v = 4*vg .. 4*vg+3
        const int rg = lane >> 4;          // rows rowbase + 4*rg + r
        const float* xr0 = x + (rowbase + rg * 4) * 240;
        float4 acc0 = {0,0,0,0}, acc1 = {0,0,0,0}, acc2 = {0,0,0,0}, acc3 = {0,0,0,0};
        #pragma unroll 4
        for (int kg = 0; kg < 16; ++kg) {          // u0 = 4*kg
            const float4 w0 = *(const float4*)&ws[(4*kg + 0) * 64 + 4*vg];
            const float4 w1 = *(const float4*)&ws[(4*kg + 1) * 64 + 4*vg];
            const float4 w2 = *(const float4*)&ws[(4*kg + 2) * 64 + 4*vg];
            const float4 w3 = *(const float4*)&ws[(4*kg + 3) * 64 + 4*vg];
            const float4 q0 = *(const float4*)(xr0 +   0 + 4*kg);
            const float4 q1 = *(const float4*)(xr0 + 240 + 4*kg);
            const float4 q2 = *(const float4*)(xr0 + 480 + 4*kg);
            const float4 q3 = *(const float4*)(xr0 + 720 + 4*kg);
            FMA4(acc0, q0, w0, w1, w2, w3);
            FMA4(acc1, q1, w0, w1, w2, w3);
            FMA4(acc2, q2, w0, w1, w2, w3);
            FMA4(acc3, q3, w0, w1, w2, w3);
        }
        float* ob = out + (rowbase + rg * 4) * 240 + 4*vg;
        const float4 s = {0.125f, 0.125f, 0.125f, 0.125f};
        float4 o;
        o.x = acc0.x*s.x; o.y = acc0.y*s.x; o.z = acc0.z*s.x; o.w = acc0.w*s.x;
        *(float4*)(ob +   0) = o;
        o.x = acc1.x*s.x; o.y = acc1.y*s.x; o.z = acc1.z*s.x; o.w = acc1.w*s.x;
        *(float4*)(ob + 240) = o;
        o.x = acc2.x*s.x; o.y = acc2.y*s.x; o.z = acc2.z*s.x; o.w = acc2.w*s.x;
        *(float4*)(ob + 480) = o;
        o.x = acc3.x*s.x; o.y = acc3.y*s.x; o.z = acc3.z*s.x; o.w = acc3.w*s.x;
        *(float4*)(ob + 720) = o;
    }

    // ============ segment 1: u=v=32, i=3, cols [64,160) ============
    // lane = 16 v-groups (2 v each) x 4 row-groups (4 rows each)
    {
        const int vg = lane & 15;          // v = 2*vg, 2*vg+1
        const int rg = lane >> 4;
        const float* xb = x + (rowbase + rg * 4) * 240 + 64;
        float acc[4][6] = {};              // [row][dv*3 + i]
        #pragma unroll 2
        for (int kg = 0; kg < 8; ++kg) {           // u0 = 4*kg
            const float2 p0 = *(const float2*)&ws[4096 + (4*kg + 0) * 32 + 2*vg];
            const float2 p1 = *(const float2*)&ws[4096 + (4*kg + 1) * 32 + 2*vg];
            const float2 p2 = *(const float2*)&ws[4096 + (4*kg + 2) * 32 + 2*vg];
            const float2 p3 = *(const float2*)&ws[4096 + (4*kg + 3) * 32 + 2*vg];
            #pragma unroll
            for (int r = 0; r < 4; ++r) {
                const float* xr = xb + r * 240 + 12*kg;
                const float4 a = *(const float4*)(xr);       // (u,i): 00 01 02 10
                const float4 b = *(const float4*)(xr + 4);   // 11 12 20 21
                const float4 c = *(const float4*)(xr + 8);   // 22 30 31 32
                acc[r][0] += a.x*p0.x + a.w*p1.x + b.z*p2.x + c.y*p3.x;
                acc[r][1] += a.y*p0.x + b.x*p1.x + b.w*p2.x + c.z*p3.x;
                acc[r][2] += a.z*p0.x + b.y*p1.x + c.x*p2.x + c.w*p3.x;
                acc[r][3] += a.x*p0.y + a.w*p1.y + b.z*p2.y + c.y*p3.y;
                acc[r][4] += a.y*p0.y + b.x*p1.y + b.w*p2.y + c.z*p3.y;
                acc[r][5] += a.z*p0.y + b.y*p1.y + c.x*p2.y + c.w*p3.y;
            }
        }
        const float s1 = 0.17677669529663687f;   // 1/sqrt(32)
        #pragma unroll
        for (int r = 0; r < 4; ++r) {
            float* op = out + (rowbase + rg * 4 + r) * 240 + 64 + 6*vg;
            *(float2*)(op + 0) = make_float2(acc[r][0]*s1, acc[r][1]*s1);
            *(float2*)(op + 2) = make_float2(acc[r][2]*s1, acc[r][3]*s1);
            *(float2*)(op + 4) = make_float2(acc[r][4]*s1, acc[r][5]*s1);
        }
    }

    // ============ segment 2: u=v=16, i=5, cols [160,240) ============
    // lane = 8 v-groups (2 v each) x 8 row-groups (2 rows each)
    {
        const int vg = lane & 7;           // v = 2*vg, 2*vg+1
        const int rg = lane >> 3;
        const float* xb = x + (rowbase + rg * 2) * 240 + 160;
        float acc[2][10] = {};             // [row][dv*5 + i]
        #pragma unroll
        for (int kg = 0; kg < 4; ++kg) {           // u0 = 4*kg
            const float2 p0 = *(const float2*)&ws[5120 + (4*kg + 0) * 16 + 2*vg];
            const float2 p1 = *(const float2*)&ws[5120 + (4*kg + 1) * 16 + 2*vg];
            const float2 p2 = *(const float2*)&ws[5120 + (4*kg + 2) * 16 + 2*vg];
            const float2 p3 = *(const float2*)&ws[5120 + (4*kg + 3) * 16 + 2*vg];
            #pragma unroll
            for (int r = 0; r < 2; ++r) {
                const float* xr = xb + r * 240 + 20*kg;
                const float4 a = *(const float4*)(xr);       // idx 0..3
                const float4 b = *(const float4*)(xr + 4);   // 4..7
                const float4 c = *(const float4*)(xr + 8);   // 8..11
                const float4 d = *(const float4*)(xr + 12);  // 12..15
                const float4 e = *(const float4*)(xr + 16);  // 16..19
                // u-series: u0: a.x a.y a.z a.w b.x | u1: b.y b.z b.w c.x c.y
                //           u2: c.z c.w d.x d.y d.z | u3: d.w e.x e.y e.z e.w
                acc[r][0] += a.x*p0.x + b.y*p1.x + c.z*p2.x + d.w*p3.x;
                acc[r][1] += a.y*p0.x + b.z*p1.x + c.w*p2.x + e.x*p3.x;
                acc[r][2] += a.z*p0.x + b.w*p1.x + d.x*p2.x + e.y*p3.x;
                acc[r][3] += a.w*p0.x + c.x*p1.x + d.y*p2.x + e.z*p3.x;
                acc[r][4] += b.x*p0.x + c.y*p1.x + d.z*p2.x + e.w*p3.x;
                acc[r][5] += a.x*p0.y + b.y*p1.y + c.z*p2.y + d.w*p3.y;
                acc[r][6] += a.y*p0.y + b.z*p1.y + c.w*p2.y + e.x*p3.y;
                acc[r][7] += a.z*p0.y + b.w*p1.y + d.x*p2.y + e.y*p3.y;
                acc[r][8] += a.w*p0.y + c.x*p1.y + d.y*p2.y + e.z*p3.y;
                acc[r][9] += b.x*p0.y + c.y*p1.y + d.z*p2.y + e.w*p3.y;
            }
        }
        #pragma unroll
        for (int r = 0; r < 2; ++r) {
            float* op = out + (rowbase + rg * 2 + r) * 240 + 160 + 10*vg;
            *(float2*)(op + 0) = make_float2(acc[r][0]*0.25f, acc[r][1]*0.25f);
            *(float2*)(op + 2) = make_float2(acc[r][2]*0.25f, acc[r][3]*0.25f);
            *(float2*)(op + 4) = make_float2(acc[r][4]*0.25f, acc[r][5]*0.25f);
            *(float2*)(op + 6) = make_float2(acc[r][6]*0.25f, acc[r][7]*0.25f);
            *(float2*)(op + 8) = make_float2(acc[r][8]*0.25f, acc[r][9]*0.25f);
        }
    }
}

extern "C" void kernel_launch(void* const* d_in, const int* in_sizes, int n_in,
                              void* d_out, int out_size, void* d_ws, size_t ws_size,
                              hipStream_t stream) {
    const float* x = (const float*)d_in[0];
    const float* w = (const float*)d_in[1];
    float* out = (float*)d_out;
    const int nrows = in_sizes[0] / 240;          // 200000
    const int blocks = nrows / RPB;               // 3125 (exact)
    eqlin_kernel<<<blocks, BLOCK, 0, stream>>>(x, w, out, nrows);
}